// Round 4
// baseline (468.698 us; speedup 1.0000x reference)
//
#include <hip/hip_runtime.h>
#include <hip/hip_cooperative_groups.h>

namespace cg = cooperative_groups;

#define NRAYS 16384
#define NLEV  16
#define THASH 524288
#define MAXACT 48
#define MAXPTS (NRAYS*MAXACT)
#define FGRID 768      // fused: 3 blocks/CU capacity target (cap is 4 @ 64 VGPR/33KB LDS)
#define MBLK  512      // fallback k_mlp
#define MGRID 1024     // fallback persistent grid

// fp32 z_i exactly as np.linspace(2,6,128) fp32: z_i = fl32(2 + fl32(i*step))
__device__ __forceinline__ float zval32(int i) {
  const float step = 4.0f / 127.0f;
  return __fadd_rn(2.0f, __fmul_rn((float)i, step));
}
__device__ __forceinline__ float pcoord(float o, float d, float z) {
  return __fadd_rn(o, __fmul_rn(d, z));
}

// ---------- shared device bodies (identical math to validated R2 kernel) ----------
__device__ __forceinline__ void classify_body(const float* __restrict__ rays,
                                              float* __restrict__ sh,
                                              unsigned* __restrict__ rn, int r) {
  float ox = rays[6*r+0], oy = rays[6*r+1], oz = rays[6*r+2];
  float dx = rays[6*r+3], dy = rays[6*r+4], dz = rays[6*r+5];
  float x = dx, y = dy, z = dz;
  float xx = x*x, yy = y*y, zz = z*z, xy = x*y, yz = y*z, xz = x*z;
  float* shp = sh + 16*r;
  shp[0]  = 0.28209479177387814f;
  shp[1]  = -0.4886025119029199f * y;
  shp[2]  =  0.4886025119029199f * z;
  shp[3]  = -0.4886025119029199f * x;
  shp[4]  =  1.0925484305920792f * xy;
  shp[5]  = -1.0925484305920792f * yz;
  shp[6]  =  0.31539156525252005f * (2.0f*zz - xx - yy);
  shp[7]  = -1.0925484305920792f * xz;
  shp[8]  =  0.5462742152960396f * (xx - yy);
  shp[9]  = -0.5900435899266435f * y * (3.0f*xx - yy);
  shp[10] =  2.890611442640554f  * xy * z;
  shp[11] = -0.4570457994644658f * y * (4.0f*zz - xx - yy);
  shp[12] =  0.3731763325901154f * z * (2.0f*zz - 3.0f*xx - 3.0f*yy);
  shp[13] = -0.4570457994644658f * x * (4.0f*zz - xx - yy);
  shp[14] =  1.445305721320277f  * z * (xx - yy);
  shp[15] = -0.5900435899266435f * x * (xx - 3.0f*yy);
  int n = 0;
  for (int i = 0; i < 128; ++i) {
    float zi = zval32(i);
    float px = pcoord(ox, dx, zi);
    float py = pcoord(oy, dy, zi);
    float pz = pcoord(oz, dz, zi);
    bool in = (px >= -1.5f) && (px <= 1.5f) && (py >= -1.5f) && (py <= 1.5f)
           && (pz >= -1.5f) && (pz <= 1.5f);
    if (!in) break;
    ++n;
  }
  rn[r] = (unsigned)n;
}

__device__ __forceinline__ void comp_body(const float* __restrict__ rays,
                                          const unsigned* __restrict__ rbase,
                                          const unsigned* __restrict__ rn,
                                          const float4* __restrict__ results,
                                          float* __restrict__ out, int r) {
  float dx = rays[6*r+3], dy = rays[6*r+4], dz = rays[6*r+5];
  float dnorm = sqrtf(dx*dx + dy*dy + dz*dz);
  int n = (int)rn[r];
  unsigned base = rbase[r];
  const float step = 4.0f/127.0f;
  const float diststep = __fmul_rn(step, dnorm);   // n<=47<127: never the 1e10 tail
  float S = 0.f, ch0 = 0.f, ch1 = 0.f, ch2 = 0.f, dep = 0.f, trans = 1.f;
  for (int i = 0; i < n; ++i) {
    float4 rs = results[base + i];
    float z = zval32(i);
    float sg = fmaxf(rs.x, 0.f);
    float alpha = -expm1f(-__fmul_rn(sg, diststep));
    float w = __fmul_rn(alpha, trans);
    trans = __fmul_rn(trans, __fadd_rn(__fsub_rn(1.f, alpha), 1e-10f));
    float s0 = 1.f/(1.f + expf(-rs.y));
    float s1 = 1.f/(1.f + expf(-rs.z));
    float s2 = 1.f/(1.f + expf(-rs.w));
    S += w; ch0 += w*s0; ch1 += w*s1; ch2 += w*s2; dep += w*z;
  }
  float rem  = __fadd_rn(__fsub_rn(1.f, S), 1e-6f);
  float Stot = __fadd_rn(S, rem);
  float loss = 0.f, trans2 = 1.f;
  for (int i = 0; i < n; ++i) {
    float4 rs = results[base + i];
    float sg = fmaxf(rs.x, 0.f);
    float alpha = -expm1f(-__fmul_rn(sg, diststep));
    float w = __fmul_rn(alpha, trans2);
    trans2 = __fmul_rn(trans2, __fadd_rn(__fsub_rn(1.f, alpha), 1e-10f));
    float p = __fdiv_rn(w, Stot);
    loss += p * logf(fmaxf(p, 1e-37f));
  }
  float pl = __fdiv_rn(rem, Stot);
  loss += pl * logf(fmaxf(pl, 1e-37f));
  out[3*r+0] = ch0; out[3*r+1] = ch1; out[3*r+2] = ch2;
  out[3*NRAYS + r] = dep;
  out[4*NRAYS + r] = -loss;
}

// MLP layer: wave q computes outputs [jbase, jbase+JC) for all 64 points.
// FMA accumulation order (k ascending per output) identical to validated kernel.
template<int IN, int TOTOUT, int JC, bool RELU>
__device__ __forceinline__ void layer(const float* __restrict__ W, int jbase,
                                      const float* __restrict__ in,
                                      float* __restrict__ out, int lane) {
  float acc[JC];
#pragma unroll
  for (int j = 0; j < JC; ++j) acc[j] = 0.0f;
#pragma unroll 8
  for (int k = 0; k < IN; ++k) {
    float a = in[k*64 + lane];
    const float* Wk = W + k*TOTOUT + jbase;
#pragma unroll
    for (int j = 0; j < JC; ++j) acc[j] = fmaf(a, Wk[j], acc[j]);
  }
#pragma unroll
  for (int j = 0; j < JC; ++j)
    out[(jbase + j)*64 + lane] = RELU ? fmaxf(acc[j], 0.0f) : acc[j];
}

__device__ __forceinline__ void mlp_tile(const float* __restrict__ rays,
                                         const float* __restrict__ tables,
                                         const float* __restrict__ w_s0,
                                         const float* __restrict__ w_s1,
                                         const float* __restrict__ w_s2,
                                         const float* __restrict__ w_c0,
                                         const float* __restrict__ w_c1,
                                         const float* __restrict__ w_c2,
                                         const float* __restrict__ w_c3,
                                         const float* __restrict__ sh,
                                         const unsigned* __restrict__ plist,
                                         float4* __restrict__ results,
                                         float* bufA, float* bufB, float* sig_s,
                                         unsigned* pid_s, unsigned count,
                                         unsigned tile, int t, int lane, int q,
                                         const float* RESF) {
  unsigned s0 = tile << 6;
  if (t < 64) {
    unsigned s = s0 + (unsigned)t;
    pid_s[t] = (s < count) ? plist[s] : 0u;
  }
  __syncthreads();
  // ---- hash gather: wave q handles levels 2q, 2q+1 -> rows 4q..4q+3 ----
  {
    unsigned pid = pid_s[lane];
    int r = (int)(pid >> 7);
    int i = (int)(pid & 127u);
    float zi = zval32(i);
    float px = pcoord(rays[6*r+0], rays[6*r+3], zi);
    float py = pcoord(rays[6*r+1], rays[6*r+4], zi);
    float pz = pcoord(rays[6*r+2], rays[6*r+5], zi);
    float xcx = fminf(fmaxf(px, -1.5f), 1.5f);
    float xcy = fminf(fmaxf(py, -1.5f), 1.5f);
    float xcz = fminf(fmaxf(pz, -1.5f), 1.5f);
#pragma unroll
    for (int li = 0; li < 2; ++li) {
      int l = 2*q + li;
      const float grid = 3.0f / RESF[l];
      float bfx = floorf(__fdiv_rn(__fadd_rn(xcx, 1.5f), grid));
      float bfy = floorf(__fdiv_rn(__fadd_rn(xcy, 1.5f), grid));
      float bfz = floorf(__fdiv_rn(__fadd_rn(xcz, 1.5f), grid));
      float vmx = __fadd_rn(__fmul_rn(bfx, grid), -1.5f);
      float vmy = __fadd_rn(__fmul_rn(bfy, grid), -1.5f);
      float vmz = __fadd_rn(__fmul_rn(bfz, grid), -1.5f);
      float wx = __fdiv_rn(__fsub_rn(xcx, vmx), grid);
      float wy = __fdiv_rn(__fsub_rn(xcy, vmy), grid);
      float wz = __fdiv_rn(__fsub_rn(xcz, vmz), grid);
      unsigned cx0 = (unsigned)(int)bfx, cy0 = (unsigned)(int)bfy, cz0 = (unsigned)(int)bfz;
      unsigned cx1 = cx0 + 1u, cy1 = cy0 + 1u, cz1 = cz0 + 1u;
      unsigned hy0 = cy0*2654435761u, hy1 = cy1*2654435761u;
      unsigned hz0 = cz0*805459861u,  hz1 = cz1*805459861u;
      const float2* tb = (const float2*)tables + (size_t)l*THASH;
      float2 e000 = tb[(cx0^hy0^hz0)&(THASH-1)];
      float2 e001 = tb[(cx0^hy0^hz1)&(THASH-1)];
      float2 e010 = tb[(cx0^hy1^hz0)&(THASH-1)];
      float2 e011 = tb[(cx0^hy1^hz1)&(THASH-1)];
      float2 e100 = tb[(cx1^hy0^hz0)&(THASH-1)];
      float2 e101 = tb[(cx1^hy0^hz1)&(THASH-1)];
      float2 e110 = tb[(cx1^hy1^hz0)&(THASH-1)];
      float2 e111 = tb[(cx1^hy1^hz1)&(THASH-1)];
      float iwx = 1.f-wx, iwy = 1.f-wy, iwz = 1.f-wz;
      float c00a = e000.x*iwx + e100.x*wx, c00b = e000.y*iwx + e100.y*wx;
      float c01a = e001.x*iwx + e101.x*wx, c01b = e001.y*iwx + e101.y*wx;
      float c10a = e010.x*iwx + e110.x*wx, c10b = e010.y*iwx + e110.y*wx;
      float c11a = e011.x*iwx + e111.x*wx, c11b = e011.y*iwx + e111.y*wx;
      float c0a = c00a*iwy + c10a*wy, c0b = c00b*iwy + c10b*wy;
      float c1a = c01a*iwy + c11a*wy, c1b = c01b*iwy + c11b*wy;
      bufA[(2*l+0)*64 + lane] = c0a*iwz + c1a*wz;
      bufA[(2*l+1)*64 + lane] = c0b*iwz + c1b*wz;
    }
  }
  __syncthreads();
  layer<32,64,8,true >(w_s0, q*8, bufA, bufB, lane); __syncthreads();
  layer<64,64,8,true >(w_s1, q*8, bufB, bufA, lane); __syncthreads();
  layer<64,16,2,false>(w_s2, q*2, bufA, bufB, lane); __syncthreads();
  if (q == 0) sig_s[lane] = bufB[0*64 + lane];
  // color input: rows 0..15 = SH, rows 16..30 = geo (bufB rows 1..15)
  for (int idx = t; idx < 31*64; idx += 512) {
    int k = idx >> 6, p = idx & 63;
    float v;
    if (k < 16) v = sh[(pid_s[p] >> 7)*16 + k];
    else        v = bufB[(k-15)*64 + p];
    bufA[idx] = v;
  }
  __syncthreads();
  layer<31,64,8,true >(w_c0, q*8, bufA, bufB, lane); __syncthreads();
  layer<64,64,8,true >(w_c1, q*8, bufB, bufA, lane); __syncthreads();
  layer<64,64,8,true >(w_c2, q*8, bufA, bufB, lane); __syncthreads();
  if (q < 3) layer<64,3,1,false>(w_c3, q, bufB, bufA, lane);
  __syncthreads();
  if (q == 0) {
    unsigned s = s0 + (unsigned)lane;
    if (s < count) {
      float4 res;
      res.x = sig_s[lane];
      res.y = bufA[0*64 + lane];
      res.z = bufA[1*64 + lane];
      res.w = bufA[2*64 + lane];
      results[s] = res;
    }
  }
  __syncthreads();
}

// ---------------- fused cooperative kernel: one dispatch, 3 grid syncs ----------
__global__ __launch_bounds__(512, 8)   // VGPR<=64 -> 4 blocks/CU capacity; grid 768 co-resident
void k_fused(const float* __restrict__ rays, const float* __restrict__ tables,
             const float* __restrict__ w_s0, const float* __restrict__ w_s1,
             const float* __restrict__ w_s2, const float* __restrict__ w_c0,
             const float* __restrict__ w_c1, const float* __restrict__ w_c2,
             const float* __restrict__ w_c3,
             float* __restrict__ sh, unsigned* __restrict__ counter,
             unsigned* __restrict__ rbase, unsigned* __restrict__ rn,
             unsigned* __restrict__ plist, float4* __restrict__ results,
             float* __restrict__ out) {
  __shared__ float bufA[64*64];
  __shared__ float bufB[64*64];
  __shared__ float sig_s[64];
  __shared__ unsigned pid_s[64];
  __shared__ unsigned wsum[8];
  const int t    = threadIdx.x;
  const int lane = t & 63;
  const int q    = __builtin_amdgcn_readfirstlane(t >> 6);
  cg::grid_group grid = cg::this_grid();

  // ---- phase 1: classify + SH (blocks 0..31 active) ----
  {
    int r = (int)blockIdx.x * 512 + t;
    if (r < NRAYS) classify_body(rays, sh, rn, r);
  }
  grid.sync();

  // ---- phase 2: scan + compaction (block 0; 512 threads x 32 rays each) ----
  if (blockIdx.x == 0) {
    const uint4* rn4 = (const uint4*)rn;
    unsigned tot = 0;
#pragma unroll
    for (int k = 0; k < 8; ++k) {
      uint4 a = rn4[t*8 + k];
      tot += a.x + a.y + a.z + a.w;
    }
    unsigned incl = tot;
#pragma unroll
    for (int off = 1; off < 64; off <<= 1) {
      unsigned v = __shfl_up(incl, off);
      if (lane >= off) incl += v;
    }
    if (lane == 63) wsum[t >> 6] = incl;
    __syncthreads();
    if (t == 0) {
      unsigned acc = 0;
#pragma unroll
      for (int w = 0; w < 8; ++w) { unsigned x = wsum[w]; wsum[w] = acc; acc += x; }
      *counter = acc;
    }
    __syncthreads();
    unsigned base = wsum[t >> 6] + (incl - tot);   // exclusive prefix
#pragma unroll
    for (int k = 0; k < 8; ++k) {
      uint4 a = rn4[t*8 + k];                      // re-read (L2-hot) to save VGPRs
      unsigned nj[4] = {a.x, a.y, a.z, a.w};
#pragma unroll
      for (int c = 0; c < 4; ++c) {
        int r = t*32 + k*4 + c;
        rbase[r] = base;
        for (unsigned i = 0; i < nj[c]; ++i) plist[base + i] = (unsigned)(r*128) + i;
        base += nj[c];
      }
    }
  }
  grid.sync();

  // ---- phase 3: MLP tiles (all 570-ish tiles fully parallel; grid-stride) ----
  {
    const unsigned count  = *counter;
    const unsigned ntiles = (count + 63u) >> 6;
    const float RESF[NLEV] = {16.f,20.f,25.f,32.f,40.f,50.f,64.f,80.f,
                              101.f,128.f,161.f,203.f,256.f,322.f,406.f,512.f};
    for (unsigned tile = blockIdx.x; tile < ntiles; tile += (unsigned)gridDim.x)
      mlp_tile(rays, tables, w_s0, w_s1, w_s2, w_c0, w_c1, w_c2, w_c3,
               sh, plist, results, bufA, bufB, sig_s, pid_s, count,
               tile, t, lane, q, RESF);
  }
  grid.sync();

  // ---- phase 4: composite (blocks 0..31 active) ----
  {
    int r = (int)blockIdx.x * 512 + t;
    if (r < NRAYS) comp_body(rays, rbase, rn, results, out, r);
  }
}

// ---------------- fallback path (validated R2 kernels) ----------------
__global__ __launch_bounds__(64)
void k_classify(const float* __restrict__ rays, float* __restrict__ sh,
                unsigned* __restrict__ rn) {
  int r = blockIdx.x * 64 + threadIdx.x;
  if (r >= NRAYS) return;
  classify_body(rays, sh, rn, r);
}

__global__ __launch_bounds__(1024)
void k_scan(const unsigned* __restrict__ rn, unsigned* __restrict__ rbase,
            unsigned* __restrict__ counter, unsigned* __restrict__ plist) {
  __shared__ unsigned wsum[16];
  const int t = threadIdx.x;
  const int lane = t & 63, wid = t >> 6;
  unsigned nv[16];
  const uint4* rn4 = (const uint4*)rn;
  unsigned tot = 0;
#pragma unroll
  for (int k = 0; k < 4; ++k) {
    uint4 a = rn4[t*4 + k];
    nv[4*k+0] = a.x; nv[4*k+1] = a.y; nv[4*k+2] = a.z; nv[4*k+3] = a.w;
    tot += a.x + a.y + a.z + a.w;
  }
  unsigned incl = tot;
#pragma unroll
  for (int off = 1; off < 64; off <<= 1) {
    unsigned v = __shfl_up(incl, off);
    if (lane >= off) incl += v;
  }
  if (lane == 63) wsum[wid] = incl;
  __syncthreads();
  if (t == 0) {
    unsigned acc = 0;
#pragma unroll
    for (int w = 0; w < 16; ++w) { unsigned x = wsum[w]; wsum[w] = acc; acc += x; }
    *counter = acc;
  }
  __syncthreads();
  unsigned base = wsum[wid] + (incl - tot);
#pragma unroll
  for (int j = 0; j < 16; ++j) {
    int r = t*16 + j;
    rbase[r] = base;
    unsigned nj = nv[j];
    for (unsigned i = 0; i < nj; ++i) plist[base + i] = (unsigned)(r*128) + i;
    base += nj;
  }
}

__global__ __launch_bounds__(MBLK)
void k_mlp(const float* __restrict__ rays, const float* __restrict__ tables,
           const float* __restrict__ w_s0, const float* __restrict__ w_s1,
           const float* __restrict__ w_s2, const float* __restrict__ w_c0,
           const float* __restrict__ w_c1, const float* __restrict__ w_c2,
           const float* __restrict__ w_c3, const float* __restrict__ sh,
           const unsigned* __restrict__ counter, const unsigned* __restrict__ plist,
           float4* __restrict__ results) {
  __shared__ float bufA[64*64];
  __shared__ float bufB[64*64];
  __shared__ float sig_s[64];
  __shared__ unsigned pid_s[64];
  const int t = threadIdx.x;
  const int lane = t & 63;
  const int q = __builtin_amdgcn_readfirstlane(t >> 6);
  const unsigned count = *counter;
  const unsigned ntiles = (count + 63u) >> 6;
  const float RESF[NLEV] = {16.f,20.f,25.f,32.f,40.f,50.f,64.f,80.f,
                            101.f,128.f,161.f,203.f,256.f,322.f,406.f,512.f};
  for (unsigned tile = blockIdx.x; tile < ntiles; tile += MGRID)
    mlp_tile(rays, tables, w_s0, w_s1, w_s2, w_c0, w_c1, w_c2, w_c3,
             sh, plist, results, bufA, bufB, sig_s, pid_s, count,
             tile, t, lane, q, RESF);
}

__global__ __launch_bounds__(64)
void k_comp(const float* __restrict__ rays, const unsigned* __restrict__ rbase,
            const unsigned* __restrict__ rn, const float4* __restrict__ results,
            float* __restrict__ out) {
  int r = blockIdx.x * 64 + threadIdx.x;
  if (r >= NRAYS) return;
  comp_body(rays, rbase, rn, results, out, r);
}

// ---------------- launch ----------------
extern "C" void kernel_launch(void* const* d_in, const int* in_sizes, int n_in,
                              void* d_out, int out_size, void* d_ws, size_t ws_size,
                              hipStream_t stream) {
  const float* rays   = (const float*)d_in[0];
  const float* tables = (const float*)d_in[1];
  const float* ws0    = (const float*)d_in[2];
  const float* ws1    = (const float*)d_in[3];
  const float* ws2    = (const float*)d_in[4];
  const float* wc0    = (const float*)d_in[5];
  const float* wc1    = (const float*)d_in[6];
  const float* wc2    = (const float*)d_in[7];
  const float* wc3    = (const float*)d_in[8];

  char* ws = (char*)d_ws;
  unsigned* counter = (unsigned*)ws;
  unsigned* rbase   = (unsigned*)(ws + 256);
  unsigned* rn      = (unsigned*)(ws + 256 + 65536);
  float*    sh      = (float*)  (ws + 256 + 131072);
  float4*   results = (float4*) (ws + 1179904);
  unsigned* plist   = (unsigned*)(ws + 1179904 + (size_t)MAXPTS*16);
  float*    outp    = (float*)d_out;

  void* kargs[] = {(void*)&rays, (void*)&tables, (void*)&ws0, (void*)&ws1,
                   (void*)&ws2, (void*)&wc0, (void*)&wc1, (void*)&wc2,
                   (void*)&wc3, (void*)&sh, (void*)&counter, (void*)&rbase,
                   (void*)&rn, (void*)&plist, (void*)&results, (void*)&outp};
  hipError_t e = hipLaunchCooperativeKernel((void*)k_fused, dim3(FGRID), dim3(512),
                                            kargs, 0, stream);
  if (e != hipSuccess) {
    // fallback: validated 4-dispatch R2 path
    k_classify<<<NRAYS/64, 64, 0, stream>>>(rays, sh, rn);
    k_scan<<<1, 1024, 0, stream>>>(rn, rbase, counter, plist);
    k_mlp<<<MGRID, MBLK, 0, stream>>>(rays, tables, ws0, ws1, ws2,
                                      wc0, wc1, wc2, wc3, sh, counter, plist, results);
    k_comp<<<NRAYS/64, 64, 0, stream>>>(rays, rbase, rn, results, outp);
  }
}

// Round 6
// 181.736 us; speedup vs baseline: 2.5790x; 2.5790x over previous
//
#include <hip/hip_runtime.h>

#define NRAYS 16384
#define NLEV  16
#define THASH 524288
#define MAXACT 48
#define MAXPTS (NRAYS*MAXACT)
#define MBLK  512      // k_mlp: 8 waves
#define MGRID 1024     // persistent grid

// clang ext-vector (layout-identical to float2) — __builtin_nontemporal_load
// requires scalar/ext-vector pointee, not HIP_vector_type.
typedef float nt2 __attribute__((ext_vector_type(2)));

// fp32 z_i exactly as np.linspace(2,6,128) fp32: z_i = fl32(2 + fl32(i*step))
__device__ __forceinline__ float zval32(int i) {
  const float step = 4.0f / 127.0f;
  return __fadd_rn(2.0f, __fmul_rn((float)i, step));
}
__device__ __forceinline__ float pcoord(float o, float d, float z) {
  return __fadd_rn(o, __fmul_rn(d, z));
}

// ---------------- kernel 1: classify rays, SH encode, compact (R0 validated) ----
__global__ __launch_bounds__(64)
void k_classify(const float* __restrict__ rays,
                float* __restrict__ sh,
                unsigned* __restrict__ counter,
                unsigned* __restrict__ rbase,
                unsigned* __restrict__ rn,
                unsigned* __restrict__ plist) {
  int r = blockIdx.x * 64 + threadIdx.x;
  if (r >= NRAYS) return;
  float ox = rays[6*r+0], oy = rays[6*r+1], oz = rays[6*r+2];
  float dx = rays[6*r+3], dy = rays[6*r+4], dz = rays[6*r+5];
  float x = dx, y = dy, z = dz;
  float xx = x*x, yy = y*y, zz = z*z, xy = x*y, yz = y*z, xz = x*z;
  float* shp = sh + 16*r;
  shp[0]  = 0.28209479177387814f;
  shp[1]  = -0.4886025119029199f * y;
  shp[2]  =  0.4886025119029199f * z;
  shp[3]  = -0.4886025119029199f * x;
  shp[4]  =  1.0925484305920792f * xy;
  shp[5]  = -1.0925484305920792f * yz;
  shp[6]  =  0.31539156525252005f * (2.0f*zz - xx - yy);
  shp[7]  = -1.0925484305920792f * xz;
  shp[8]  =  0.5462742152960396f * (xx - yy);
  shp[9]  = -0.5900435899266435f * y * (3.0f*xx - yy);
  shp[10] =  2.890611442640554f  * xy * z;
  shp[11] = -0.4570457994644658f * y * (4.0f*zz - xx - yy);
  shp[12] =  0.3731763325901154f * z * (2.0f*zz - 3.0f*xx - 3.0f*yy);
  shp[13] = -0.4570457994644658f * x * (4.0f*zz - xx - yy);
  shp[14] =  1.445305721320277f  * z * (xx - yy);
  shp[15] = -0.5900435899266435f * x * (xx - 3.0f*yy);
  // fp32 in-box prefix count (box convex, o inside => in-box samples are a prefix)
  int n = 0;
  for (int i = 0; i < 128; ++i) {
    float zi = zval32(i);
    float px = pcoord(ox, dx, zi);
    float py = pcoord(oy, dy, zi);
    float pz = pcoord(oz, dz, zi);
    bool in = (px >= -1.5f) && (px <= 1.5f) && (py >= -1.5f) && (py <= 1.5f)
           && (pz >= -1.5f) && (pz <= 1.5f);
    if (!in) break;
    ++n;
  }
  unsigned base = atomicAdd(counter, (unsigned)n);
  rbase[r] = base;
  rn[r]    = (unsigned)n;
  for (int i = 0; i < n; ++i) plist[base + i] = (unsigned)(r*128 + i);
}

// ---------------- kernel 2: cooperative tile MLP ----------------
// unroll 8: 8 wave-uniform s_load weight fetches in flight. FMA order per
// output is k-ascending fmaf -> bit-exact vs validated kernel.
template<int IN, int TOTOUT, int JC, bool RELU>
__device__ __forceinline__ void layer(const float* __restrict__ W, int jbase,
                                      const float* __restrict__ in,
                                      float* __restrict__ out, int lane) {
  float acc[JC];
#pragma unroll
  for (int j = 0; j < JC; ++j) acc[j] = 0.0f;
#pragma unroll 8
  for (int k = 0; k < IN; ++k) {
    float a = in[k*64 + lane];
    const float* Wk = W + k*TOTOUT + jbase;
#pragma unroll
    for (int j = 0; j < JC; ++j) acc[j] = fmaf(a, Wk[j], acc[j]);
  }
#pragma unroll
  for (int j = 0; j < JC; ++j)
    out[(jbase + j)*64 + lane] = RELU ? fmaxf(acc[j], 0.0f) : acc[j];
}

__global__ __launch_bounds__(MBLK)
void k_mlp(const float* __restrict__ rays,
           const float* __restrict__ tables,
           const float* __restrict__ w_s0, const float* __restrict__ w_s1,
           const float* __restrict__ w_s2, const float* __restrict__ w_c0,
           const float* __restrict__ w_c1, const float* __restrict__ w_c2,
           const float* __restrict__ w_c3,
           const float* __restrict__ sh,
           const unsigned* __restrict__ counter,
           const unsigned* __restrict__ plist,
           float4* __restrict__ results) {
  __shared__ float bufA[64*64];
  __shared__ float bufB[64*64];
  __shared__ float sig_s[64];
  __shared__ unsigned pid_s[64];
  const int t = threadIdx.x;
  const int lane = t & 63;
  const int q = __builtin_amdgcn_readfirstlane(t >> 6);   // wave id 0..7
  // ---- L2 warm: stream all weights (70KB) so per-layer s_loads hit warm L2 ----
  {
    float pf = 0.f;
    const float4* a;
    a = (const float4*)w_s0; for (int i = t; i < 512;  i += MBLK) pf += a[i].x;
    a = (const float4*)w_s1; for (int i = t; i < 1024; i += MBLK) pf += a[i].x;
    a = (const float4*)w_s2; for (int i = t; i < 256;  i += MBLK) pf += a[i].x;
    a = (const float4*)w_c0; for (int i = t; i < 496;  i += MBLK) pf += a[i].x;
    a = (const float4*)w_c1; for (int i = t; i < 1024; i += MBLK) pf += a[i].x;
    a = (const float4*)w_c2; for (int i = t; i < 1024; i += MBLK) pf += a[i].x;
    a = (const float4*)w_c3; for (int i = t; i < 48;   i += MBLK) pf += a[i].x;
    asm volatile("" :: "v"(pf));   // keep loads alive
  }
  const unsigned count = *counter;
  const unsigned ntiles = (count + 63u) >> 6;
  const float RESF[NLEV] = {16.f,20.f,25.f,32.f,40.f,50.f,64.f,80.f,
                            101.f,128.f,161.f,203.f,256.f,322.f,406.f,512.f};
  for (unsigned tile = blockIdx.x; tile < ntiles; tile += MGRID) {
    unsigned s0 = tile << 6;
    if (t < 64) {
      unsigned s = s0 + (unsigned)t;
      pid_s[t] = (s < count) ? plist[s] : 0u;
    }
    __syncthreads();
    // ---- hash gather: wave q handles levels 2q, 2q+1 -> rows 4q..4q+3 ----
    {
      unsigned pid = pid_s[lane];
      int r = (int)(pid >> 7);
      int i = (int)(pid & 127u);
      float zi = zval32(i);
      float px = pcoord(rays[6*r+0], rays[6*r+3], zi);
      float py = pcoord(rays[6*r+1], rays[6*r+4], zi);
      float pz = pcoord(rays[6*r+2], rays[6*r+5], zi);
      float xcx = fminf(fmaxf(px, -1.5f), 1.5f);
      float xcy = fminf(fmaxf(py, -1.5f), 1.5f);
      float xcz = fminf(fmaxf(pz, -1.5f), 1.5f);
#pragma unroll
      for (int li = 0; li < 2; ++li) {
        int l = 2*q + li;
        const float grid = 3.0f / RESF[l];
        float bfx = floorf(__fdiv_rn(__fadd_rn(xcx, 1.5f), grid));
        float bfy = floorf(__fdiv_rn(__fadd_rn(xcy, 1.5f), grid));
        float bfz = floorf(__fdiv_rn(__fadd_rn(xcz, 1.5f), grid));
        float vmx = __fadd_rn(__fmul_rn(bfx, grid), -1.5f);
        float vmy = __fadd_rn(__fmul_rn(bfy, grid), -1.5f);
        float vmz = __fadd_rn(__fmul_rn(bfz, grid), -1.5f);
        float wx = __fdiv_rn(__fsub_rn(xcx, vmx), grid);
        float wy = __fdiv_rn(__fsub_rn(xcy, vmy), grid);
        float wz = __fdiv_rn(__fsub_rn(xcz, vmz), grid);
        unsigned cx0 = (unsigned)(int)bfx, cy0 = (unsigned)(int)bfy, cz0 = (unsigned)(int)bfz;
        unsigned cx1 = cx0 + 1u, cy1 = cy0 + 1u, cz1 = cz0 + 1u;
        unsigned hy0 = cy0*2654435761u, hy1 = cy1*2654435761u;
        unsigned hz0 = cz0*805459861u,  hz1 = cz1*805459861u;
        const nt2* tb = (const nt2*)tables + (size_t)l*THASH;
        unsigned i000 = (cx0^hy0^hz0)&(THASH-1);
        unsigned i001 = (cx0^hy0^hz1)&(THASH-1);
        unsigned i010 = (cx0^hy1^hz0)&(THASH-1);
        unsigned i011 = (cx0^hy1^hz1)&(THASH-1);
        unsigned i100 = (cx1^hy0^hz0)&(THASH-1);
        unsigned i101 = (cx1^hy0^hz1)&(THASH-1);
        unsigned i110 = (cx1^hy1^hz0)&(THASH-1);
        unsigned i111 = (cx1^hy1^hz1)&(THASH-1);
        nt2 e000, e001, e010, e011, e100, e101, e110, e111;
        if (l >= 8) {
          // fine levels: mostly-unique lines; evict-first so weights stay L2-resident
          e000 = __builtin_nontemporal_load(tb + i000);
          e001 = __builtin_nontemporal_load(tb + i001);
          e010 = __builtin_nontemporal_load(tb + i010);
          e011 = __builtin_nontemporal_load(tb + i011);
          e100 = __builtin_nontemporal_load(tb + i100);
          e101 = __builtin_nontemporal_load(tb + i101);
          e110 = __builtin_nontemporal_load(tb + i110);
          e111 = __builtin_nontemporal_load(tb + i111);
        } else {
          // coarse levels: heavy cross-point reuse; keep cached
          e000 = tb[i000]; e001 = tb[i001]; e010 = tb[i010]; e011 = tb[i011];
          e100 = tb[i100]; e101 = tb[i101]; e110 = tb[i110]; e111 = tb[i111];
        }
        float iwx = 1.f-wx, iwy = 1.f-wy, iwz = 1.f-wz;
        float c00a = e000.x*iwx + e100.x*wx, c00b = e000.y*iwx + e100.y*wx;
        float c01a = e001.x*iwx + e101.x*wx, c01b = e001.y*iwx + e101.y*wx;
        float c10a = e010.x*iwx + e110.x*wx, c10b = e010.y*iwx + e110.y*wx;
        float c11a = e011.x*iwx + e111.x*wx, c11b = e011.y*iwx + e111.y*wx;
        float c0a = c00a*iwy + c10a*wy, c0b = c00b*iwy + c10b*wy;
        float c1a = c01a*iwy + c11a*wy, c1b = c01b*iwy + c11b*wy;
        bufA[(2*l+0)*64 + lane] = c0a*iwz + c1a*wz;
        bufA[(2*l+1)*64 + lane] = c0b*iwz + c1b*wz;
      }
    }
    __syncthreads();
    layer<32,64,8,true >(w_s0, q*8, bufA, bufB, lane); __syncthreads();
    layer<64,64,8,true >(w_s1, q*8, bufB, bufA, lane); __syncthreads();
    layer<64,16,2,false>(w_s2, q*2, bufA, bufB, lane); __syncthreads();
    if (q == 0) sig_s[lane] = bufB[0*64 + lane];
    // color input: rows 0..15 = SH, rows 16..30 = geo (bufB rows 1..15)
    for (int idx = t; idx < 31*64; idx += MBLK) {
      int k = idx >> 6, p = idx & 63;
      float v;
      if (k < 16) v = sh[(pid_s[p] >> 7)*16 + k];
      else        v = bufB[(k-15)*64 + p];
      bufA[idx] = v;
    }
    __syncthreads();
    layer<31,64,8,true >(w_c0, q*8, bufA, bufB, lane); __syncthreads();
    layer<64,64,8,true >(w_c1, q*8, bufB, bufA, lane); __syncthreads();
    layer<64,64,8,true >(w_c2, q*8, bufA, bufB, lane); __syncthreads();
    if (q < 3) layer<64,3,1,false>(w_c3, q, bufB, bufA, lane);
    __syncthreads();
    if (q == 0) {
      unsigned s = s0 + (unsigned)lane;
      if (s < count) {
        float4 res;
        res.x = sig_s[lane];
        res.y = bufA[0*64 + lane];
        res.z = bufA[1*64 + lane];
        res.w = bufA[2*64 + lane];
        results[s] = res;
      }
    }
    __syncthreads();
  }
}

// ---------------- kernel 3: composite (R0 validated per-lane version) ----------
__global__ __launch_bounds__(64)
void k_comp(const float* __restrict__ rays,
            const unsigned* __restrict__ rbase,
            const unsigned* __restrict__ rn,
            const float4* __restrict__ results,
            float* __restrict__ out) {
  int r = blockIdx.x * 64 + threadIdx.x;
  if (r >= NRAYS) return;
  float dx = rays[6*r+3], dy = rays[6*r+4], dz = rays[6*r+5];
  float dnorm = sqrtf(dx*dx + dy*dy + dz*dz);
  int n = (int)rn[r];
  unsigned base = rbase[r];
  const float step = 4.0f/127.0f;
  const float diststep = __fmul_rn(step, dnorm);   // n<=47<127: never the 1e10 tail
  float S = 0.f, ch0 = 0.f, ch1 = 0.f, ch2 = 0.f, dep = 0.f, trans = 1.f;
  for (int i = 0; i < n; ++i) {
    float4 rs = results[base + i];
    float z = zval32(i);
    float sg = fmaxf(rs.x, 0.f);
    float alpha = -expm1f(-__fmul_rn(sg, diststep));
    float w = __fmul_rn(alpha, trans);
    trans = __fmul_rn(trans, __fadd_rn(__fsub_rn(1.f, alpha), 1e-10f));
    float s0 = 1.f/(1.f + expf(-rs.y));
    float s1 = 1.f/(1.f + expf(-rs.z));
    float s2 = 1.f/(1.f + expf(-rs.w));
    S += w; ch0 += w*s0; ch1 += w*s1; ch2 += w*s2; dep += w*z;
  }
  float rem  = __fadd_rn(__fsub_rn(1.f, S), 1e-6f);
  float Stot = __fadd_rn(S, rem);
  float loss = 0.f, trans2 = 1.f;
  for (int i = 0; i < n; ++i) {
    float4 rs = results[base + i];
    float sg = fmaxf(rs.x, 0.f);
    float alpha = -expm1f(-__fmul_rn(sg, diststep));
    float w = __fmul_rn(alpha, trans2);
    trans2 = __fmul_rn(trans2, __fadd_rn(__fsub_rn(1.f, alpha), 1e-10f));
    float p = __fdiv_rn(w, Stot);
    loss += p * logf(fmaxf(p, 1e-37f));
  }
  float pl = __fdiv_rn(rem, Stot);
  loss += pl * logf(fmaxf(pl, 1e-37f));
  out[3*r+0] = ch0; out[3*r+1] = ch1; out[3*r+2] = ch2;
  out[3*NRAYS + r] = dep;
  out[4*NRAYS + r] = -loss;
}

// ---------------- launch (R0 structure) ----------------
extern "C" void kernel_launch(void* const* d_in, const int* in_sizes, int n_in,
                              void* d_out, int out_size, void* d_ws, size_t ws_size,
                              hipStream_t stream) {
  const float* rays   = (const float*)d_in[0];
  const float* tables = (const float*)d_in[1];
  const float* ws0    = (const float*)d_in[2];
  const float* ws1    = (const float*)d_in[3];
  const float* ws2    = (const float*)d_in[4];
  const float* wc0    = (const float*)d_in[5];
  const float* wc1    = (const float*)d_in[6];
  const float* wc2    = (const float*)d_in[7];
  const float* wc3    = (const float*)d_in[8];

  char* ws = (char*)d_ws;
  unsigned* counter = (unsigned*)ws;
  unsigned* rbase   = (unsigned*)(ws + 256);
  unsigned* rn      = (unsigned*)(ws + 256 + 65536);
  float*    sh      = (float*)  (ws + 256 + 131072);
  float4*   results = (float4*) (ws + 1179904);
  unsigned* plist   = (unsigned*)(ws + 1179904 + (size_t)MAXPTS*16);

  (void)hipMemsetAsync(counter, 0, 4, stream);
  k_classify<<<NRAYS/64, 64, 0, stream>>>(rays, sh, counter, rbase, rn, plist);
  k_mlp<<<MGRID, MBLK, 0, stream>>>(rays, tables, ws0, ws1, ws2,
                                    wc0, wc1, wc2, wc3, sh, counter, plist, results);
  k_comp<<<NRAYS/64, 64, 0, stream>>>(rays, rbase, rn, results, (float*)d_out);
}

// Round 7
// 181.268 us; speedup vs baseline: 2.5857x; 1.0026x over previous
//
#include <hip/hip_runtime.h>

#define NRAYS 16384
#define NLEV  16
#define THASH 524288
#define MAXACT 48
#define MAXPTS (NRAYS*MAXACT)
#define MBLK  512      // k_mlp: 8 waves
#define MGRID 1024     // persistent grid

// clang ext-vector (layout-identical to float2) — __builtin_nontemporal_load
// requires scalar/ext-vector pointee, not HIP_vector_type.
typedef float nt2 __attribute__((ext_vector_type(2)));

// fp32 z_i exactly as np.linspace(2,6,128) fp32: z_i = fl32(2 + fl32(i*step))
__device__ __forceinline__ float zval32(int i) {
  const float step = 4.0f / 127.0f;
  return __fadd_rn(2.0f, __fmul_rn((float)i, step));
}
__device__ __forceinline__ float pcoord(float o, float d, float z) {
  return __fadd_rn(o, __fmul_rn(d, z));
}

// ---------------- kernel 1: classify rays, SH encode, compact (R0 validated) ----
__global__ __launch_bounds__(64)
void k_classify(const float* __restrict__ rays,
                float* __restrict__ sh,
                unsigned* __restrict__ counter,
                unsigned* __restrict__ rbase,
                unsigned* __restrict__ rn,
                unsigned* __restrict__ plist) {
  int r = blockIdx.x * 64 + threadIdx.x;
  if (r >= NRAYS) return;
  float ox = rays[6*r+0], oy = rays[6*r+1], oz = rays[6*r+2];
  float dx = rays[6*r+3], dy = rays[6*r+4], dz = rays[6*r+5];
  float x = dx, y = dy, z = dz;
  float xx = x*x, yy = y*y, zz = z*z, xy = x*y, yz = y*z, xz = x*z;
  float* shp = sh + 16*r;
  shp[0]  = 0.28209479177387814f;
  shp[1]  = -0.4886025119029199f * y;
  shp[2]  =  0.4886025119029199f * z;
  shp[3]  = -0.4886025119029199f * x;
  shp[4]  =  1.0925484305920792f * xy;
  shp[5]  = -1.0925484305920792f * yz;
  shp[6]  =  0.31539156525252005f * (2.0f*zz - xx - yy);
  shp[7]  = -1.0925484305920792f * xz;
  shp[8]  =  0.5462742152960396f * (xx - yy);
  shp[9]  = -0.5900435899266435f * y * (3.0f*xx - yy);
  shp[10] =  2.890611442640554f  * xy * z;
  shp[11] = -0.4570457994644658f * y * (4.0f*zz - xx - yy);
  shp[12] =  0.3731763325901154f * z * (2.0f*zz - 3.0f*xx - 3.0f*yy);
  shp[13] = -0.4570457994644658f * x * (4.0f*zz - xx - yy);
  shp[14] =  1.445305721320277f  * z * (xx - yy);
  shp[15] = -0.5900435899266435f * x * (xx - 3.0f*yy);
  // fp32 in-box prefix count (box convex, o inside => in-box samples are a prefix)
  int n = 0;
  for (int i = 0; i < 128; ++i) {
    float zi = zval32(i);
    float px = pcoord(ox, dx, zi);
    float py = pcoord(oy, dy, zi);
    float pz = pcoord(oz, dz, zi);
    bool in = (px >= -1.5f) && (px <= 1.5f) && (py >= -1.5f) && (py <= 1.5f)
           && (pz >= -1.5f) && (pz <= 1.5f);
    if (!in) break;
    ++n;
  }
  unsigned base = atomicAdd(counter, (unsigned)n);
  rbase[r] = base;
  rn[r]    = (unsigned)n;
  for (int i = 0; i < n; ++i) plist[base + i] = (unsigned)(r*128 + i);
}

// ---------------- kernel 2: cooperative tile MLP ----------------
// unroll 8: 8 wave-uniform s_load weight fetches in flight. FMA order per
// output is k-ascending fmaf -> bit-exact vs validated kernel.
template<int IN, int TOTOUT, int JC, bool RELU>
__device__ __forceinline__ void layer(const float* __restrict__ W, int jbase,
                                      const float* __restrict__ in,
                                      float* __restrict__ out, int lane) {
  float acc[JC];
#pragma unroll
  for (int j = 0; j < JC; ++j) acc[j] = 0.0f;
#pragma unroll 8
  for (int k = 0; k < IN; ++k) {
    float a = in[k*64 + lane];
    const float* Wk = W + k*TOTOUT + jbase;
#pragma unroll
    for (int j = 0; j < JC; ++j) acc[j] = fmaf(a, Wk[j], acc[j]);
  }
#pragma unroll
  for (int j = 0; j < JC; ++j)
    out[(jbase + j)*64 + lane] = RELU ? fmaxf(acc[j], 0.0f) : acc[j];
}

// launch_bounds(512,4): VGPR cap 128 (2 blocks/CU) — room to keep all 16
// gather loads in flight (36-VGPR build could only hold ~8 -> queue-depth limit).
__global__ __launch_bounds__(MBLK, 4)
void k_mlp(const float* __restrict__ rays,
           const float* __restrict__ tables,
           const float* __restrict__ w_s0, const float* __restrict__ w_s1,
           const float* __restrict__ w_s2, const float* __restrict__ w_c0,
           const float* __restrict__ w_c1, const float* __restrict__ w_c2,
           const float* __restrict__ w_c3,
           const float* __restrict__ sh,
           const unsigned* __restrict__ counter,
           const unsigned* __restrict__ plist,
           float4* __restrict__ results) {
  __shared__ float bufA[64*64];
  __shared__ float bufB[64*64];
  __shared__ float sig_s[64];
  __shared__ unsigned pid_s[64];
  const int t = threadIdx.x;
  const int lane = t & 63;
  const int q = __builtin_amdgcn_readfirstlane(t >> 6);   // wave id 0..7
  const unsigned count = *counter;
  const unsigned ntiles = (count + 63u) >> 6;
  if ((unsigned)blockIdx.x >= ntiles) return;   // drop workless blocks early
  // ---- L2 warm: stream all weights (70KB) so per-layer s_loads hit warm L2 ----
  {
    float pf = 0.f;
    const float4* a;
    a = (const float4*)w_s0; for (int i = t; i < 512;  i += MBLK) pf += a[i].x;
    a = (const float4*)w_s1; for (int i = t; i < 1024; i += MBLK) pf += a[i].x;
    a = (const float4*)w_s2; for (int i = t; i < 256;  i += MBLK) pf += a[i].x;
    a = (const float4*)w_c0; for (int i = t; i < 496;  i += MBLK) pf += a[i].x;
    a = (const float4*)w_c1; for (int i = t; i < 1024; i += MBLK) pf += a[i].x;
    a = (const float4*)w_c2; for (int i = t; i < 1024; i += MBLK) pf += a[i].x;
    a = (const float4*)w_c3; for (int i = t; i < 48;   i += MBLK) pf += a[i].x;
    asm volatile("" :: "v"(pf));   // keep loads alive
  }
  const float RESF[NLEV] = {16.f,20.f,25.f,32.f,40.f,50.f,64.f,80.f,
                            101.f,128.f,161.f,203.f,256.f,322.f,406.f,512.f};
  for (unsigned tile = blockIdx.x; tile < ntiles; tile += MGRID) {
    unsigned s0 = tile << 6;
    if (t < 64) {
      unsigned s = s0 + (unsigned)t;
      pid_s[t] = (s < count) ? plist[s] : 0u;
    }
    __syncthreads();
    // ---- hash gather: wave q handles levels 2q, 2q+1 -> rows 4q..4q+3 ----
    // Restructured: ALL 16 indices computed, ALL 16 loads issued, THEN lerp.
    // Same loaded values + same lerp expression order -> bit-exact.
    {
      unsigned pid = pid_s[lane];
      int r = (int)(pid >> 7);
      int i = (int)(pid & 127u);
      float zi = zval32(i);
      float px = pcoord(rays[6*r+0], rays[6*r+3], zi);
      float py = pcoord(rays[6*r+1], rays[6*r+4], zi);
      float pz = pcoord(rays[6*r+2], rays[6*r+5], zi);
      float xcx = fminf(fmaxf(px, -1.5f), 1.5f);
      float xcy = fminf(fmaxf(py, -1.5f), 1.5f);
      float xcz = fminf(fmaxf(pz, -1.5f), 1.5f);
      float wxa[2], wya[2], wza[2];
      unsigned idx[2][8];
#pragma unroll
      for (int li = 0; li < 2; ++li) {
        int l = 2*q + li;
        const float grid = 3.0f / RESF[l];
        float bfx = floorf(__fdiv_rn(__fadd_rn(xcx, 1.5f), grid));
        float bfy = floorf(__fdiv_rn(__fadd_rn(xcy, 1.5f), grid));
        float bfz = floorf(__fdiv_rn(__fadd_rn(xcz, 1.5f), grid));
        float vmx = __fadd_rn(__fmul_rn(bfx, grid), -1.5f);
        float vmy = __fadd_rn(__fmul_rn(bfy, grid), -1.5f);
        float vmz = __fadd_rn(__fmul_rn(bfz, grid), -1.5f);
        wxa[li] = __fdiv_rn(__fsub_rn(xcx, vmx), grid);
        wya[li] = __fdiv_rn(__fsub_rn(xcy, vmy), grid);
        wza[li] = __fdiv_rn(__fsub_rn(xcz, vmz), grid);
        unsigned cx0 = (unsigned)(int)bfx, cy0 = (unsigned)(int)bfy, cz0 = (unsigned)(int)bfz;
        unsigned cx1 = cx0 + 1u, cy1 = cy0 + 1u, cz1 = cz0 + 1u;
        unsigned hy0 = cy0*2654435761u, hy1 = cy1*2654435761u;
        unsigned hz0 = cz0*805459861u,  hz1 = cz1*805459861u;
        idx[li][0] = (cx0^hy0^hz0)&(THASH-1);
        idx[li][1] = (cx0^hy0^hz1)&(THASH-1);
        idx[li][2] = (cx0^hy1^hz0)&(THASH-1);
        idx[li][3] = (cx0^hy1^hz1)&(THASH-1);
        idx[li][4] = (cx1^hy0^hz0)&(THASH-1);
        idx[li][5] = (cx1^hy0^hz1)&(THASH-1);
        idx[li][6] = (cx1^hy1^hz0)&(THASH-1);
        idx[li][7] = (cx1^hy1^hz1)&(THASH-1);
      }
      nt2 e[2][8];
      if (q >= 4) {   // wave-uniform: both levels >=8 -> evict-first fine levels
#pragma unroll
        for (int li = 0; li < 2; ++li) {
          const nt2* tb = (const nt2*)tables + (size_t)(2*q+li)*THASH;
#pragma unroll
          for (int c = 0; c < 8; ++c)
            e[li][c] = __builtin_nontemporal_load(tb + idx[li][c]);
        }
      } else {        // coarse levels: heavy reuse, keep cached
#pragma unroll
        for (int li = 0; li < 2; ++li) {
          const nt2* tb = (const nt2*)tables + (size_t)(2*q+li)*THASH;
#pragma unroll
          for (int c = 0; c < 8; ++c)
            e[li][c] = tb[idx[li][c]];
        }
      }
      asm volatile("" ::: "memory");   // keep all 16 loads issued before lerp
#pragma unroll
      for (int li = 0; li < 2; ++li) {
        int l = 2*q + li;
        float wx = wxa[li], wy = wya[li], wz = wza[li];
        float iwx = 1.f-wx, iwy = 1.f-wy, iwz = 1.f-wz;
        float c00a = e[li][0].x*iwx + e[li][4].x*wx, c00b = e[li][0].y*iwx + e[li][4].y*wx;
        float c01a = e[li][1].x*iwx + e[li][5].x*wx, c01b = e[li][1].y*iwx + e[li][5].y*wx;
        float c10a = e[li][2].x*iwx + e[li][6].x*wx, c10b = e[li][2].y*iwx + e[li][6].y*wx;
        float c11a = e[li][3].x*iwx + e[li][7].x*wx, c11b = e[li][3].y*iwx + e[li][7].y*wx;
        float c0a = c00a*iwy + c10a*wy, c0b = c00b*iwy + c10b*wy;
        float c1a = c01a*iwy + c11a*wy, c1b = c01b*iwy + c11b*wy;
        bufA[(2*l+0)*64 + lane] = c0a*iwz + c1a*wz;
        bufA[(2*l+1)*64 + lane] = c0b*iwz + c1b*wz;
      }
    }
    __syncthreads();
    layer<32,64,8,true >(w_s0, q*8, bufA, bufB, lane); __syncthreads();
    layer<64,64,8,true >(w_s1, q*8, bufB, bufA, lane); __syncthreads();
    layer<64,16,2,false>(w_s2, q*2, bufA, bufB, lane); __syncthreads();
    if (q == 0) sig_s[lane] = bufB[0*64 + lane];
    // color input: rows 0..15 = SH, rows 16..30 = geo (bufB rows 1..15)
    for (int idx2 = t; idx2 < 31*64; idx2 += MBLK) {
      int k = idx2 >> 6, p = idx2 & 63;
      float v;
      if (k < 16) v = sh[(pid_s[p] >> 7)*16 + k];
      else        v = bufB[(k-15)*64 + p];
      bufA[idx2] = v;
    }
    __syncthreads();
    layer<31,64,8,true >(w_c0, q*8, bufA, bufB, lane); __syncthreads();
    layer<64,64,8,true >(w_c1, q*8, bufB, bufA, lane); __syncthreads();
    layer<64,64,8,true >(w_c2, q*8, bufA, bufB, lane); __syncthreads();
    if (q < 3) layer<64,3,1,false>(w_c3, q, bufB, bufA, lane);
    __syncthreads();
    if (q == 0) {
      unsigned s = s0 + (unsigned)lane;
      if (s < count) {
        float4 res;
        res.x = sig_s[lane];
        res.y = bufA[0*64 + lane];
        res.z = bufA[1*64 + lane];
        res.w = bufA[2*64 + lane];
        results[s] = res;
      }
    }
    __syncthreads();
  }
}

// ---------------- kernel 3: composite (R0 validated per-lane version) ----------
__global__ __launch_bounds__(64)
void k_comp(const float* __restrict__ rays,
            const unsigned* __restrict__ rbase,
            const unsigned* __restrict__ rn,
            const float4* __restrict__ results,
            float* __restrict__ out) {
  int r = blockIdx.x * 64 + threadIdx.x;
  if (r >= NRAYS) return;
  float dx = rays[6*r+3], dy = rays[6*r+4], dz = rays[6*r+5];
  float dnorm = sqrtf(dx*dx + dy*dy + dz*dz);
  int n = (int)rn[r];
  unsigned base = rbase[r];
  const float step = 4.0f/127.0f;
  const float diststep = __fmul_rn(step, dnorm);   // n<=47<127: never the 1e10 tail
  float S = 0.f, ch0 = 0.f, ch1 = 0.f, ch2 = 0.f, dep = 0.f, trans = 1.f;
  for (int i = 0; i < n; ++i) {
    float4 rs = results[base + i];
    float z = zval32(i);
    float sg = fmaxf(rs.x, 0.f);
    float alpha = -expm1f(-__fmul_rn(sg, diststep));
    float w = __fmul_rn(alpha, trans);
    trans = __fmul_rn(trans, __fadd_rn(__fsub_rn(1.f, alpha), 1e-10f));
    float s0 = 1.f/(1.f + expf(-rs.y));
    float s1 = 1.f/(1.f + expf(-rs.z));
    float s2 = 1.f/(1.f + expf(-rs.w));
    S += w; ch0 += w*s0; ch1 += w*s1; ch2 += w*s2; dep += w*z;
  }
  float rem  = __fadd_rn(__fsub_rn(1.f, S), 1e-6f);
  float Stot = __fadd_rn(S, rem);
  float loss = 0.f, trans2 = 1.f;
  for (int i = 0; i < n; ++i) {
    float4 rs = results[base + i];
    float sg = fmaxf(rs.x, 0.f);
    float alpha = -expm1f(-__fmul_rn(sg, diststep));
    float w = __fmul_rn(alpha, trans2);
    trans2 = __fmul_rn(trans2, __fadd_rn(__fsub_rn(1.f, alpha), 1e-10f));
    float p = __fdiv_rn(w, Stot);
    loss += p * logf(fmaxf(p, 1e-37f));
  }
  float pl = __fdiv_rn(rem, Stot);
  loss += pl * logf(fmaxf(pl, 1e-37f));
  out[3*r+0] = ch0; out[3*r+1] = ch1; out[3*r+2] = ch2;
  out[3*NRAYS + r] = dep;
  out[4*NRAYS + r] = -loss;
}

// ---------------- launch (R0 structure) ----------------
extern "C" void kernel_launch(void* const* d_in, const int* in_sizes, int n_in,
                              void* d_out, int out_size, void* d_ws, size_t ws_size,
                              hipStream_t stream) {
  const float* rays   = (const float*)d_in[0];
  const float* tables = (const float*)d_in[1];
  const float* ws0    = (const float*)d_in[2];
  const float* ws1    = (const float*)d_in[3];
  const float* ws2    = (const float*)d_in[4];
  const float* wc0    = (const float*)d_in[5];
  const float* wc1    = (const float*)d_in[6];
  const float* wc2    = (const float*)d_in[7];
  const float* wc3    = (const float*)d_in[8];

  char* ws = (char*)d_ws;
  unsigned* counter = (unsigned*)ws;
  unsigned* rbase   = (unsigned*)(ws + 256);
  unsigned* rn      = (unsigned*)(ws + 256 + 65536);
  float*    sh      = (float*)  (ws + 256 + 131072);
  float4*   results = (float4*) (ws + 1179904);
  unsigned* plist   = (unsigned*)(ws + 1179904 + (size_t)MAXPTS*16);

  (void)hipMemsetAsync(counter, 0, 4, stream);
  k_classify<<<NRAYS/64, 64, 0, stream>>>(rays, sh, counter, rbase, rn, plist);
  k_mlp<<<MGRID, MBLK, 0, stream>>>(rays, tables, ws0, ws1, ws2,
                                    wc0, wc1, wc2, wc3, sh, counter, plist, results);
  k_comp<<<NRAYS/64, 64, 0, stream>>>(rays, rbase, rn, results, (float*)d_out);
}